// Round 9
// baseline (1773.807 us; speedup 1.0000x reference)
//
#include <hip/hip_runtime.h>
#include <math.h>

#define NW 5
#define NS 5
#define CDIM 640
#define HWDIM 1024
#define BDIM 25
#define CAP 24
constexpr int CHW = CDIM * HWDIM;                 // 655360
constexpr int NBIG = BDIM * CHW;                  // 16,384,000 elems
constexpr int WSZ = CDIM * CDIM;                  // 409,600
constexpr int NROWS = NW * NS * NS * HWDIM;       // 128000 (w,ks,sq,q)
constexpr float QK_SCALE = 0.03952847075210474f;  // 1/sqrt(640)
constexpr float TWOE_COEF = 0.016f;               // rigorous 2*(2*2^-8) bound

typedef __attribute__((ext_vector_type(4))) float f32x4;
typedef __attribute__((ext_vector_type(8))) __bf16 bf16x8;
typedef __attribute__((ext_vector_type(4))) __bf16 bf16x4;
typedef __attribute__((ext_vector_type(2))) __bf16 bf16x2;

__device__ __forceinline__ void load_lds16(const __bf16* g, __bf16* l) {
    __builtin_amdgcn_global_load_lds(
        (const __attribute__((address_space(1))) void*)g,
        (__attribute__((address_space(3))) void*)l, 16, 0, 0);
}

// ---------------------------------------------------------------------------
// split fp32 -> (hi, lo) bf16, same layout. n4 = n/4.
// ---------------------------------------------------------------------------
__global__ __launch_bounds__(256) void split_f32(const float* __restrict__ s,
                                                 __bf16* __restrict__ dH,
                                                 __bf16* __restrict__ dL, int n4) {
    int i = blockIdx.x * 256 + threadIdx.x;
    if (i >= n4) return;
    f32x4 v = reinterpret_cast<const f32x4*>(s)[i];
    bf16x4 h, lo;
    #pragma unroll
    for (int q = 0; q < 4; ++q) {
        __bf16 hh = (__bf16)v[q];
        h[q] = hh;
        lo[q] = (__bf16)(v[q] - (float)hh);
    }
    reinterpret_cast<bf16x4*>(dH)[i] = h;
    reinterpret_cast<bf16x4*>(dL)[i] = lo;
}

// ---------------------------------------------------------------------------
// transpose [b][c][hw] fp32 -> [b][hw][c] (hi,lo) bf16. 32x32 tiles.
// ---------------------------------------------------------------------------
__global__ __launch_bounds__(256) void tsplit(const float* __restrict__ x,
                                              __bf16* __restrict__ dH,
                                              __bf16* __restrict__ dL) {
    __shared__ float sT[32][33];
    const int hw0 = blockIdx.x * 32, c0 = blockIdx.y * 32, b = blockIdx.z;
    const int t = threadIdx.x;
    const int r = t >> 3, q4 = (t & 7) * 4;
    f32x4 v = *reinterpret_cast<const f32x4*>(
        &x[(size_t)b * CHW + (size_t)(c0 + r) * HWDIM + hw0 + q4]);
    #pragma unroll
    for (int i = 0; i < 4; ++i) sT[r][q4 + i] = v[i];
    __syncthreads();
    bf16x4 h, lo;
    #pragma unroll
    for (int i = 0; i < 4; ++i) {
        float xv = sT[q4 + i][r];
        __bf16 hh = (__bf16)xv;
        h[i] = hh;
        lo[i] = (__bf16)(xv - (float)hh);
    }
    size_t off = (size_t)b * CHW + (size_t)(hw0 + r) * CDIM + c0 + q4;
    *reinterpret_cast<bf16x4*>(&dH[off]) = h;
    *reinterpret_cast<bf16x4*>(&dL[off]) = lo;
}

// ---------------------------------------------------------------------------
// transposed split of (Wc + I): out[ci][t] = Wc[t][ci] + (t==ci), hi/lo bf16.
// ---------------------------------------------------------------------------
__global__ __launch_bounds__(256) void wtsplit(const float* __restrict__ W,
                                               __bf16* __restrict__ dH,
                                               __bf16* __restrict__ dL) {
    __shared__ float sT[32][33];
    const int ci0 = blockIdx.x * 32, t0 = blockIdx.y * 32;
    const int t = threadIdx.x;
    const int r = t >> 3, q4 = (t & 7) * 4;
    f32x4 v = *reinterpret_cast<const f32x4*>(&W[(size_t)(t0 + r) * CDIM + ci0 + q4]);
    #pragma unroll
    for (int i = 0; i < 4; ++i) sT[r][q4 + i] = v[i];
    __syncthreads();
    bf16x4 h, lo;
    #pragma unroll
    for (int i = 0; i < 4; ++i) {
        float xv = sT[q4 + i][r];  // = W[t0+q4+i][ci0+r]
        if (t0 + q4 + i == ci0 + r) xv += 1.0f;
        __bf16 hh = (__bf16)xv;
        h[i] = hh;
        lo[i] = (__bf16)(xv - (float)hh);
    }
    size_t off = (size_t)(ci0 + r) * CDIM + t0 + q4;
    *reinterpret_cast<bf16x4*>(&dH[off]) = h;
    *reinterpret_cast<bf16x4*>(&dL[off]) = lo;
}

// bias prep: zbias=0, B2 = Wq*bc + bq, bb2 = [bq, bk]. one block of 640.
__global__ void bias_prep(const float* __restrict__ Wq, const float* __restrict__ bc,
                          const float* __restrict__ bq, const float* __restrict__ bk,
                          float* __restrict__ zbias, float* __restrict__ B2,
                          float* __restrict__ bb2) {
    const int o = threadIdx.x;
    zbias[o] = 0.0f;
    float s = bq[o];
    for (int t = 0; t < CDIM; ++t) s = fmaf(Wq[(size_t)o * CDIM + t], bc[t], s);
    B2[o] = s;
    bb2[o] = bq[o];
    bb2[CDIM + o] = bk[o];
}

// ===========================================================================
// hi+lo swizzled staging (convs): rows of 64 bf16 (cols 0-31 hi, 32-63 lo),
// physical 16B-chunk = logical ^ (row&7) via pre-swizzled global source.
// ===========================================================================
template <int NL>
__device__ __forceinline__ void stage_rows(const __bf16* __restrict__ srcH,
                                           const __bf16* __restrict__ srcL,
                                           __bf16* lds, int wv, int l, int c0) {
    const int lch = (l & 7) ^ (l >> 3);
    const int scol = (lch & 3) * 8;
    const int srw = l >> 3;
    const __bf16* src = (lch & 4) ? srcL : srcH;
    #pragma unroll
    for (int i = 0; i < NL; ++i) {
        const int r0 = wv * (8 * NL) + i * 8;
        load_lds16(&src[(size_t)(r0 + srw) * CDIM + c0 + scol], &lds[r0 * 64]);
    }
}

// ===========================================================================
// hi-only rowpair staging (attn): tile = [RP rowpairs][128B]; rowpair rp holds
// rows 2rp,2rp+1 as 8 chunks, physical chunk = logical ^ (rp&7). One load
// covers 8 rowpairs. Read: elems = (r>>1)*64 + ((((r&1)*4+c)^((r>>1)&7))*8.
// ===========================================================================
__device__ __forceinline__ void stage_hi(const __bf16* __restrict__ src,
                                         __bf16* lds, int li, int l) {
    const int rp = li * 8 + (l >> 3);
    const int pc = l & 7;
    const int lc = pc ^ (rp & 7);
    const int srow = 2 * rp + (lc >> 2);
    const int schan = (lc & 3) * 8;
    load_lds16(&src[(size_t)srow * CDIM + schan], &lds[li * 512]);
}

// ---------------------------------------------------------------------------
// small split-GEMM (W2 = Wq * (Wc+I)).
// ---------------------------------------------------------------------------
__global__ __launch_bounds__(256) void gemm_sm(
    const __bf16* __restrict__ inH, const __bf16* __restrict__ inL,
    const __bf16* __restrict__ wH, const __bf16* __restrict__ wL,
    const float* __restrict__ bias,
    __bf16* __restrict__ outH, __bf16* __restrict__ outL) {
    __shared__ __bf16 sA[128 * 64];
    __shared__ __bf16 sB[128 * 64];
    const int hw0 = blockIdx.x * 128;
    const int o0 = blockIdx.y * 128;
    const int tid = threadIdx.x;
    const int wv = tid >> 6, l = tid & 63;
    const int wo = (wv >> 1) * 64, wh = (wv & 1) * 64;

    const __bf16* wSrcH = wH + (size_t)o0 * CDIM;
    const __bf16* wSrcL = wL + (size_t)o0 * CDIM;
    const __bf16* iSrcH = inH + (size_t)hw0 * CDIM;
    const __bf16* iSrcL = inL + (size_t)hw0 * CDIM;

    f32x4 acc[4][4];
    #pragma unroll
    for (int i = 0; i < 4; ++i)
        #pragma unroll
        for (int j = 0; j < 4; ++j) acc[i][j] = (f32x4){0.f, 0.f, 0.f, 0.f};

    const int fr = l & 15, cf = l >> 4;
    const int ehi = (cf ^ (fr & 7)) * 8;

    for (int c0 = 0; c0 < CDIM; c0 += 32) {
        stage_rows<4>(wSrcH, wSrcL, sA, wv, l, c0);
        stage_rows<4>(iSrcH, iSrcL, sB, wv, l, c0);
        __syncthreads();
        bf16x8 aH[4], aL[4], bH[4], bL[4];
        #pragma unroll
        for (int i = 0; i < 4; ++i) {
            const int ra = (wo + i * 16 + fr) * 64;
            const int rb = (wh + i * 16 + fr) * 64;
            aH[i] = *reinterpret_cast<const bf16x8*>(&sA[ra + ehi]);
            aL[i] = *reinterpret_cast<const bf16x8*>(&sA[ra + (ehi ^ 32)]);
            bH[i] = *reinterpret_cast<const bf16x8*>(&sB[rb + ehi]);
            bL[i] = *reinterpret_cast<const bf16x8*>(&sB[rb + (ehi ^ 32)]);
        }
        #pragma unroll
        for (int i = 0; i < 4; ++i)
            #pragma unroll
            for (int j = 0; j < 4; ++j) {
                acc[i][j] = __builtin_amdgcn_mfma_f32_16x16x32_bf16(
                    aH[i], bH[j], acc[i][j], 0, 0, 0);
                acc[i][j] = __builtin_amdgcn_mfma_f32_16x16x32_bf16(
                    aH[i], bL[j], acc[i][j], 0, 0, 0);
                acc[i][j] = __builtin_amdgcn_mfma_f32_16x16x32_bf16(
                    aL[i], bH[j], acc[i][j], 0, 0, 0);
            }
        __syncthreads();
    }

    const int og = (l >> 4) * 4;
    const int cl = l & 15;
    #pragma unroll
    for (int i = 0; i < 4; ++i) {
        const int o = o0 + wo + i * 16 + og;
        const f32x4 bs = *reinterpret_cast<const f32x4*>(&bias[o]);
        #pragma unroll
        for (int j = 0; j < 4; ++j) {
            const int hw = hw0 + wh + j * 16 + cl;
            const size_t off = (size_t)hw * CDIM + o;
            bf16x4 oh, ol;
            #pragma unroll
            for (int q = 0; q < 4; ++q) {
                float r = acc[i][j][q] + bs[q];
                __bf16 hh = (__bf16)r;
                oh[q] = hh;
                ol[q] = (__bf16)(r - (float)hh);
            }
            *reinterpret_cast<bf16x4*>(&outH[off]) = oh;
            *reinterpret_cast<bf16x4*>(&outL[off]) = ol;
        }
    }
}

// ---------------------------------------------------------------------------
// big conv: block tile 128o x 256hw, 4 waves of 64o x 128hw, split (hi+lo).
// ---------------------------------------------------------------------------
__global__ __launch_bounds__(256, 2) void conv_big(
    const __bf16* __restrict__ inH, const __bf16* __restrict__ inL,
    const __bf16* __restrict__ A0h, const __bf16* __restrict__ A0l,
    const __bf16* __restrict__ A1h, const __bf16* __restrict__ A1l,
    const float* __restrict__ bias,
    __bf16* __restrict__ O0h, __bf16* __restrict__ O0l,
    __bf16* __restrict__ O1h, __bf16* __restrict__ O1l) {
    __shared__ __bf16 sA[128 * 64];
    __shared__ __bf16 sB[256 * 64];
    const int hw0 = blockIdx.x * 256;
    const int oy = blockIdx.y;
    const int seg = oy / 5;
    const int o0 = (oy % 5) * 128;
    const int b = blockIdx.z;
    const int tid = threadIdx.x;
    const int wv = tid >> 6, l = tid & 63;
    const int wo = (wv >> 1) * 64;
    const int wh = (wv & 1) * 128;
    const size_t inBase = (size_t)b * CHW;

    const __bf16* Ah = seg ? A1h : A0h;
    const __bf16* Al = seg ? A1l : A0l;
    __bf16* OhP = seg ? O1h : O0h;
    __bf16* OlP = seg ? O1l : O0l;
    const __bf16* aSrcH = Ah + (size_t)o0 * CDIM;
    const __bf16* aSrcL = Al + (size_t)o0 * CDIM;
    const __bf16* bSrcH = inH + inBase + (size_t)hw0 * CDIM;
    const __bf16* bSrcL = inL + inBase + (size_t)hw0 * CDIM;

    f32x4 acc[4][8];
    #pragma unroll
    for (int i = 0; i < 4; ++i)
        #pragma unroll
        for (int j = 0; j < 8; ++j) acc[i][j] = (f32x4){0.f, 0.f, 0.f, 0.f};

    const int fr = l & 15, cf = l >> 4;
    const int ehi = (cf ^ (fr & 7)) * 8;

    for (int c0 = 0; c0 < CDIM; c0 += 32) {
        stage_rows<4>(aSrcH, aSrcL, sA, wv, l, c0);
        stage_rows<8>(bSrcH, bSrcL, sB, wv, l, c0);
        __syncthreads();
        bf16x8 aH[4], aL[4];
        #pragma unroll
        for (int i = 0; i < 4; ++i) {
            const int ra = (wo + i * 16 + fr) * 64;
            aH[i] = *reinterpret_cast<const bf16x8*>(&sA[ra + ehi]);
            aL[i] = *reinterpret_cast<const bf16x8*>(&sA[ra + (ehi ^ 32)]);
        }
        #pragma unroll
        for (int jh = 0; jh < 2; ++jh) {
            bf16x8 bH[4], bL[4];
            #pragma unroll
            for (int jj = 0; jj < 4; ++jj) {
                const int rb = (wh + (jh * 4 + jj) * 16 + fr) * 64;
                bH[jj] = *reinterpret_cast<const bf16x8*>(&sB[rb + ehi]);
                bL[jj] = *reinterpret_cast<const bf16x8*>(&sB[rb + (ehi ^ 32)]);
            }
            #pragma unroll
            for (int i = 0; i < 4; ++i)
                #pragma unroll
                for (int jj = 0; jj < 4; ++jj) {
                    const int j = jh * 4 + jj;
                    acc[i][j] = __builtin_amdgcn_mfma_f32_16x16x32_bf16(
                        aH[i], bH[jj], acc[i][j], 0, 0, 0);
                    acc[i][j] = __builtin_amdgcn_mfma_f32_16x16x32_bf16(
                        aH[i], bL[jj], acc[i][j], 0, 0, 0);
                    acc[i][j] = __builtin_amdgcn_mfma_f32_16x16x32_bf16(
                        aL[i], bH[jj], acc[i][j], 0, 0, 0);
                }
        }
        __syncthreads();
    }

    const int og = (l >> 4) * 4;
    const int cl = l & 15;
    #pragma unroll
    for (int i = 0; i < 4; ++i) {
        const int oLoc = o0 + wo + i * 16 + og;
        const f32x4 bs = *reinterpret_cast<const f32x4*>(&bias[oy * 128 + wo + i * 16 + og]);
        #pragma unroll
        for (int j = 0; j < 8; ++j) {
            const int hw = hw0 + wh + j * 16 + cl;
            const size_t off = inBase + (size_t)hw * CDIM + oLoc;
            bf16x4 oh, ol;
            #pragma unroll
            for (int q = 0; q < 4; ++q) {
                float r = acc[i][j][q] + bs[q];
                __bf16 hh = (__bf16)r;
                oh[q] = hh;
                ol[q] = (__bf16)(r - (float)hh);
            }
            *reinterpret_cast<bf16x4*>(&OhP[off]) = oh;
            *reinterpret_cast<bf16x4*>(&OlP[off]) = ol;
        }
    }
}

// ---------------------------------------------------------------------------
// row norms for xq and xk: qn[row]=|q|_2, knrow[row]=|k|_2 (hi+lo).
// grid 3200: 0..1599 -> xq, 1600..3199 -> xk. block 256 = 16 rows x 16 lanes.
// ---------------------------------------------------------------------------
__global__ __launch_bounds__(256) void qknorm_k(const __bf16* __restrict__ xqH,
                                                const __bf16* __restrict__ xqL,
                                                const __bf16* __restrict__ xkH,
                                                const __bf16* __restrict__ xkL,
                                                float* __restrict__ qn,
                                                float* __restrict__ knrow) {
    const int gb = blockIdx.x;
    const __bf16 *H, *L;
    float* dst;
    int row;
    if (gb < 1600) {
        H = xqH; L = xqL; dst = qn;
        row = gb * 16 + (threadIdx.x >> 4);
    } else {
        H = xkH; L = xkL; dst = knrow;
        row = (gb - 1600) * 16 + (threadIdx.x >> 4);
    }
    const int cq = threadIdx.x & 15;
    const size_t base = (size_t)row * CDIM;
    float s = 0.f;
    #pragma unroll
    for (int i = 0; i < 10; ++i) {
        int c = i * 64 + cq * 4;
        bf16x4 h = *reinterpret_cast<const bf16x4*>(&H[base + c]);
        bf16x4 lo = *reinterpret_cast<const bf16x4*>(&L[base + c]);
        #pragma unroll
        for (int q = 0; q < 4; ++q) {
            float x = (float)h[q] + (float)lo[q];
            s = fmaf(x, x, s);
        }
    }
    s += __shfl_xor(s, 1);
    s += __shfl_xor(s, 2);
    s += __shfl_xor(s, 4);
    s += __shfl_xor(s, 8);
    if (cq == 0) dst[row] = sqrtf(s);
}

// kmax[b] = max over 1024 rows of knrow for (w,ks)=b. grid 25, block 256.
__global__ __launch_bounds__(256) void kmax_k(const float* __restrict__ knrow,
                                              float* __restrict__ kmax) {
    const int b = blockIdx.x, tid = threadIdx.x;
    __shared__ float sm[256];
    const float* p = knrow + b * 1024;
    float v = fmaxf(fmaxf(p[tid], p[tid + 256]), fmaxf(p[tid + 512], p[tid + 768]));
    sm[tid] = v;
    __syncthreads();
    for (int s = 128; s > 0; s >>= 1) {
        if (tid < s) sm[tid] = fmaxf(sm[tid], sm[tid + s]);
        __syncthreads();
    }
    if (tid == 0) kmax[b] = sm[0];
}

// ---------------------------------------------------------------------------
// attn pass A: hi-only bf16 scores, 1 MFMA per fragment pair. Per (q,ks):
// block-wide running max (cross-wave exchange via sM); append candidate keys
// (s~ >= runmax - 2E) to global list. grid (40, 5, 5), block 256,
// tile 128q x 256k, 4 kc chunks.
// ---------------------------------------------------------------------------
__global__ __launch_bounds__(256, 2) void attn_bf16(
    const __bf16* __restrict__ qH, const __bf16* __restrict__ kH,
    const float* __restrict__ qn, const float* __restrict__ kmax,
    int* __restrict__ candCnt, unsigned short* __restrict__ candIdx) {
    __shared__ __bf16 sQ[64 * 64];   // 64 rowpairs (128 q rows) x 128B
    __shared__ __bf16 sK[128 * 64];  // 128 rowpairs (256 k rows) x 128B
    __shared__ float sM[2][128];     // per-kh chunk maxes for cross-wave share
    const int qt = blockIdx.x;
    const int ks = blockIdx.y, wy = blockIdx.z;
    const int sq = qt >> 3, q0 = (qt & 7) * 128;
    const int tid = threadIdx.x;
    const int wv = tid >> 6, l = tid & 63;
    const int wq = (wv >> 1) * 64;
    const int kh = wv & 1;
    const int wk = kh * 128;
    const __bf16* qSrc = qH + (size_t)(wy * NS + sq) * CHW + (size_t)q0 * CDIM;
    const __bf16* kBase = kH + (size_t)(wy * NS + ks) * CHW;

    const int fr = l & 15, cg = l >> 4;  // cg = chunk index (8-chan group)
    const int rowBase = ((wy * NS + ks) * NS + sq) * HWDIM + q0;

    // per-lane thresholds: 2E = coef * |q| * kmax + eps
    const float kmv = kmax[wy * NS + ks];
    float twoE[4][4];
    float run[4][4];
    #pragma unroll
    for (int i = 0; i < 4; ++i)
        #pragma unroll
        for (int qq = 0; qq < 4; ++qq) {
            int qloc = wq + i * 16 + (cg << 2) + qq;
            twoE[i][qq] = TWOE_COEF * qn[(wy * NS + sq) * HWDIM + q0 + qloc] * kmv + 1e-6f;
            run[i][qq] = -INFINITY;
        }

    // read offsets: off(r,cg) = (r>>1)*64 + (((r&1)*4+cg)^((r>>1)&7))*8
    const int rq2 = fr >> 1, par = fr & 1;
    const int xorm = rq2 & 7;
    const int cA = (wq / 2 + rq2) * 64 + (((par << 2) | cg) ^ xorm) * 8;   // + i*512
    const int cB = (wk / 2 + rq2) * 64 + (((par << 2) | cg) ^ xorm) * 8;   // + j*512

    for (int kc = 0; kc < 4; ++kc) {
        const __bf16* kSrc = kBase + (size_t)(kc * 256) * CDIM;
        f32x4 acc[4][8];
        #pragma unroll
        for (int i = 0; i < 4; ++i)
            #pragma unroll
            for (int j = 0; j < 8; ++j) acc[i][j] = (f32x4){0.f, 0.f, 0.f, 0.f};

        for (int c0 = 0; c0 < CDIM; c0 += 32) {
            stage_hi(qSrc + c0, sQ, wv * 2 + 0, l);
            stage_hi(qSrc + c0, sQ, wv * 2 + 1, l);
            #pragma unroll
            for (int li = 0; li < 4; ++li) stage_hi(kSrc + c0, sK, wv * 4 + li, l);
            __syncthreads();
            bf16x8 aH[4], bH[8];
            #pragma unroll
            for (int i = 0; i < 4; ++i)
                aH[i] = *reinterpret_cast<const bf16x8*>(&sQ[cA + i * 512]);
            #pragma unroll
            for (int j = 0; j < 8; ++j)
                bH[j] = *reinterpret_cast<const bf16x8*>(&sK[cB + j * 512]);
            __builtin_amdgcn_s_setprio(1);
            #pragma unroll
            for (int i = 0; i < 4; ++i)
                #pragma unroll
                for (int j = 0; j < 8; ++j)
                    acc[i][j] = __builtin_amdgcn_mfma_f32_16x16x32_bf16(
                        aH[i], bH[j], acc[i][j], 0, 0, 0);
            __builtin_amdgcn_s_setprio(0);
            __syncthreads();
        }
        // per-row chunk max -> publish to sM (both kh halves)
        #pragma unroll
        for (int i = 0; i < 4; ++i)
            #pragma unroll
            for (int qq = 0; qq < 4; ++qq) {
                float m = acc[i][0][qq];
                #pragma unroll
                for (int j = 1; j < 8; ++j) m = fmaxf(m, acc[i][j][qq]);
                m = fmaxf(m, __shfl_xor(m, 1));
                m = fmaxf(m, __shfl_xor(m, 2));
                m = fmaxf(m, __shfl_xor(m, 4));
                m = fmaxf(m, __shfl_xor(m, 8));
                if (fr == 0)
                    sM[kh][wq + i * 16 + (cg << 2) + qq] = m;
            }
        __syncthreads();
        // combine both waves' maxes -> block-wide running max -> appends
        #pragma unroll
        for (int i = 0; i < 4; ++i)
            #pragma unroll
            for (int qq = 0; qq < 4; ++qq) {
                const int rloc = wq + i * 16 + (cg << 2) + qq;
                run[i][qq] = fmaxf(run[i][qq],
                                   fmaxf(sM[0][rloc], sM[1][rloc]));
                const float th = run[i][qq] - twoE[i][qq];
                const int rowid = rowBase + rloc;
                #pragma unroll
                for (int j = 0; j < 8; ++j) {
                    if (acc[i][j][qq] >= th) {
                        int key = kc * 256 + wk + j * 16 + fr;
                        int slot = atomicAdd(&candCnt[rowid], 1);
                        if (slot < CAP)
                            candIdx[rowid * CAP + slot] = (unsigned short)key;
                    }
                }
            }
    }
}

// ---------------------------------------------------------------------------
// refine: exact (hi+lo) scores for candidates -> exact row max -> gpart.
// one wave per (q,ks) row; 64 lanes x 10 channels. grid NROWS/4, block 256.
// ---------------------------------------------------------------------------
__global__ __launch_bounds__(256) void refine_k(
    const __bf16* __restrict__ qH, const __bf16* __restrict__ qL,
    const __bf16* __restrict__ kH, const __bf16* __restrict__ kL,
    const int* __restrict__ candCnt, const unsigned short* __restrict__ candIdx,
    float* __restrict__ gpart) {
    const int tid = threadIdx.x, wv = tid >> 6, l = tid & 63;
    const int rowid = blockIdx.x * 4 + wv;
    const int wks = rowid / (NS * HWDIM);
    const int rem = rowid - wks * (NS * HWDIM);
    const int sq = rem >> 10, qp = rem & 1023;
    const int w = wks / NS;
    const __bf16* qh = qH + (size_t)(w * NS + sq) * CHW + (size_t)qp * CDIM;
    const __bf16* ql = qL + (size_t)(w * NS + sq) * CHW + (size_t)qp * CDIM;
    const __bf16* kb = kH + (size_t)wks * CHW;
    const __bf16* kbl = kL + (size_t)wks * CHW;

    float qv[10];
    #pragma unroll
    for (int e = 0; e < 10; ++e) {
        int c = l * 10 + e;
        qv[e] = (float)qh[c] + (float)ql[c];
    }
    const int cnt = candCnt[rowid];
    float smax = -INFINITY;
    if (cnt <= CAP) {
        for (int e = 0; e < cnt; ++e) {
            const int key = candIdx[rowid * CAP + e];
            const __bf16* kr = kb + (size_t)key * CDIM;
            const __bf16* krl = kbl + (size_t)key * CDIM;
            float s = 0.f;
            #pragma unroll
            for (int u = 0; u < 10; ++u) {
                int c = l * 10 + u;
                s = fmaf(qv[u], (float)kr[c] + (float)krl[c], s);
            }
            s += __shfl_xor(s, 1);
            s += __shfl_xor(s, 2);
            s += __shfl_xor(s, 4);
            s += __shfl_xor(s, 8);
            s += __shfl_xor(s, 16);
            s += __shfl_xor(s, 32);
            smax = fmaxf(smax, s);
        }
    } else {
        // overflow fallback: exact scan of all 1024 keys (effectively never)
        for (int key = 0; key < 1024; ++key) {
            const __bf16* kr = kb + (size_t)key * CDIM;
            const __bf16* krl = kbl + (size_t)key * CDIM;
            float s = 0.f;
            #pragma unroll
            for (int u = 0; u < 10; ++u) {
                int c = l * 10 + u;
                s = fmaf(qv[u], (float)kr[c] + (float)krl[c], s);
            }
            s += __shfl_xor(s, 1);
            s += __shfl_xor(s, 2);
            s += __shfl_xor(s, 4);
            s += __shfl_xor(s, 8);
            s += __shfl_xor(s, 16);
            s += __shfl_xor(s, 32);
            smax = fmaxf(smax, s);
        }
    }
    if (l == 0) gpart[rowid] = smax * QK_SCALE;
}

// ---------------------------------------------------------------------------
// mean over key shots -> softmax over hw per (way, sq) -> argmax mask indices
// ---------------------------------------------------------------------------
__global__ __launch_bounds__(256) void softmax_mask(const float* __restrict__ gpart,
                                                    int* __restrict__ gIdx,
                                                    int* __restrict__ gCnt) {
    const int bb = blockIdx.x;
    const int w = bb / NS, sq = bb % NS;
    const int tid = threadIdx.x;
    __shared__ float sred[256];
    __shared__ int sCnt;

    float v[4];
    #pragma unroll
    for (int i = 0; i < 4; ++i) {
        int hw = tid + 256 * i;
        float s = 0.f;
        #pragma unroll
        for (int ks = 0; ks < NS; ++ks)
            s += gpart[(size_t)(w * NS + ks) * (NS * HWDIM) + sq * HWDIM + hw];
        v[i] = s * 0.2f;
    }
    float m = fmaxf(fmaxf(v[0], v[1]), fmaxf(v[2], v[3]));
    sred[tid] = m;
    __syncthreads();
    for (int s = 128; s > 0; s >>= 1) {
        if (tid < s) sred[tid] = fmaxf(sred[tid], sred[tid + s]);
        __syncthreads();
    }
    float rowmax = sred[0];
    __syncthreads();
    float e[4], ls = 0.f;
    #pragma unroll
    for (int i = 0; i < 4; ++i) { e[i] = expf(v[i] - rowmax); ls += e[i]; }
    sred[tid] = ls;
    __syncthreads();
    for (int s = 128; s > 0; s >>= 1) {
        if (tid < s) sred[tid] += sred[tid + s];
        __syncthreads();
    }
    float ssum = sred[0];
    __syncthreads();
    float p[4], pm = 0.f;
    #pragma unroll
    for (int i = 0; i < 4; ++i) { p[i] = e[i] / ssum; pm = fmaxf(pm, p[i]); }
    sred[tid] = pm;
    __syncthreads();
    for (int s = 128; s > 0; s >>= 1) {
        if (tid < s) sred[tid] = fmaxf(sred[tid], sred[tid + s]);
        __syncthreads();
    }
    float pmax = sred[0];
    if (tid == 0) sCnt = 0;
    __syncthreads();
    #pragma unroll
    for (int i = 0; i < 4; ++i) {
        if (p[i] == pmax) {
            int slot = atomicAdd(&sCnt, 1);
            gIdx[bb * HWDIM + slot] = tid + 256 * i;
        }
    }
    __syncthreads();
    if (tid == 0) gCnt[bb] = sCnt;
}

// ---------------------------------------------------------------------------
// inv_nrm per (bb,hw): 1/max(sqrt(sum_c y^2), eps). grid 1600, block 256.
// ---------------------------------------------------------------------------
__global__ __launch_bounds__(256) void nrm_k(const __bf16* __restrict__ yH,
                                             const __bf16* __restrict__ yL,
                                             float* __restrict__ inv) {
    const int row = blockIdx.x * 16 + (threadIdx.x >> 4);
    const int cq = threadIdx.x & 15;
    const size_t base = (size_t)row * CDIM;
    float s = 0.f;
    #pragma unroll
    for (int i = 0; i < 10; ++i) {
        int c = i * 64 + cq * 4;
        bf16x4 h = *reinterpret_cast<const bf16x4*>(&yH[base + c]);
        bf16x4 lo = *reinterpret_cast<const bf16x4*>(&yL[base + c]);
        #pragma unroll
        for (int q = 0; q < 4; ++q) {
            float x = (float)h[q] + (float)lo[q];
            s = fmaf(x, x, s);
        }
    }
    s += __shfl_xor(s, 1);
    s += __shfl_xor(s, 2);
    s += __shfl_xor(s, 4);
    s += __shfl_xor(s, 8);
    if (cq == 0) inv[row] = 1.0f / fmaxf(sqrtf(s), 1e-12f);
}

// ---------------------------------------------------------------------------
// seeds[bb,c] = sum over masked hw of y[bb,hw,c]*inv[bb,hw]. grid 25, blk 640.
// ---------------------------------------------------------------------------
__global__ __launch_bounds__(640) void seeds_k(const __bf16* __restrict__ yH,
                                               const __bf16* __restrict__ yL,
                                               const float* __restrict__ inv,
                                               const int* __restrict__ gIdx,
                                               const int* __restrict__ gCnt,
                                               float* __restrict__ seeds) {
    const int bb = blockIdx.x, c = threadIdx.x;
    const int cnt = gCnt[bb];
    float s = 0.f;
    for (int e = 0; e < cnt; ++e) {
        int hw = gIdx[bb * HWDIM + e];
        size_t off = (size_t)bb * CHW + (size_t)hw * CDIM + c;
        s += ((float)yH[off] + (float)yL[off]) * inv[bb * HWDIM + hw];
    }
    seeds[bb * CDIM + c] = s;
}

// ---------------------------------------------------------------------------
// cm[way,o,hw] = sum_k inv[(way,k),hw] * sum_c y[(way,k),hw,c]*seeds[o*5+k,c]
// ---------------------------------------------------------------------------
__global__ __launch_bounds__(256) void cm_k(const __bf16* __restrict__ yH,
                                            const __bf16* __restrict__ yL,
                                            const float* __restrict__ inv,
                                            const float* __restrict__ seeds,
                                            float* __restrict__ cm) {
    __shared__ float sS[BDIM * CDIM];
    const int way = blockIdx.y;
    const int tid = threadIdx.x, wv = tid >> 6, l = tid & 63;
    const int hw = blockIdx.x * 4 + wv;
    for (int e = tid; e < BDIM * CDIM; e += 256) sS[e] = seeds[e];
    __syncthreads();
    float acc[NW] = {0.f, 0.f, 0.f, 0.f, 0.f};
    for (int k = 0; k < NS; ++k) {
        const size_t base = (size_t)(way * NS + k) * CHW + (size_t)hw * CDIM;
        float t[NW] = {0.f, 0.f, 0.f, 0.f, 0.f};
        #pragma unroll
        for (int i = 0; i < 5; ++i) {
            int c = (i * 64 + l) * 2;
            bf16x2 h = *reinterpret_cast<const bf16x2*>(&yH[base + c]);
            bf16x2 lo = *reinterpret_cast<const bf16x2*>(&yL[base + c]);
            float x0 = (float)h[0] + (float)lo[0];
            float x1 = (float)h[1] + (float)lo[1];
            #pragma unroll
            for (int o = 0; o < NW; ++o) {
                t[o] = fmaf(x0, sS[(o * NS + k) * CDIM + c], t[o]);
                t[o] = fmaf(x1, sS[(o * NS + k) * CDIM + c + 1], t[o]);
            }
        }
        float iv = inv[(way * NS + k) * HWDIM + hw];
        #pragma unroll
        for (int o = 0; o < NW; ++o) acc[o] = fmaf(t[o], iv, acc[o]);
    }
    #pragma unroll
    for (int o = 0; o < NW; ++o) {
        float v = acc[o];
        v += __shfl_xor(v, 1);
        v += __shfl_xor(v, 2);
        v += __shfl_xor(v, 4);
        v += __shfl_xor(v, 8);
        v += __shfl_xor(v, 16);
        v += __shfl_xor(v, 32);
        if (l == 0) cm[(size_t)(way * NW + o) * HWDIM + hw] = v;
    }
}

// ---------------------------------------------------------------------------
// in-place min-max normalize each row of 1024. grid 25, block 256.
// ---------------------------------------------------------------------------
__global__ __launch_bounds__(256) void minmax_kernel(float* __restrict__ cm) {
    const int row = blockIdx.x;
    const int tid = threadIdx.x;
    __shared__ float smn[256], smx[256];
    float v[4];
    #pragma unroll
    for (int i = 0; i < 4; ++i) v[i] = cm[(size_t)row * HWDIM + tid + 256 * i];
    float mn = fminf(fminf(v[0], v[1]), fminf(v[2], v[3]));
    float mx = fmaxf(fmaxf(v[0], v[1]), fmaxf(v[2], v[3]));
    smn[tid] = mn;
    smx[tid] = mx;
    __syncthreads();
    for (int s = 128; s > 0; s >>= 1) {
        if (tid < s) {
            smn[tid] = fminf(smn[tid], smn[tid + s]);
            smx[tid] = fmaxf(smx[tid], smx[tid + s]);
        }
        __syncthreads();
    }
    float cmin = smn[0], cmax = smx[0];
    float den = cmax - cmin + 1e-12f;
    #pragma unroll
    for (int i = 0; i < 4; ++i)
        cm[(size_t)row * HWDIM + tid + 256 * i] = (v[i] - cmin) / den;
}

// ---------------------------------------------------------------------------
// proto partials + reduce.
// ---------------------------------------------------------------------------
__global__ __launch_bounds__(128) void proto_part_k(const __bf16* __restrict__ yH,
                                                    const __bf16* __restrict__ yL,
                                                    const float* __restrict__ cmn,
                                                    float* __restrict__ part) {
    const int w = blockIdx.x, cc = blockIdx.y, hs = blockIdx.z;
    const int c = cc * 128 + threadIdx.x;
    float s = 0.f;
    for (int i = 0; i < 640; ++i) {
        int g = hs * 640 + i, sh = g >> 10, hw = g & 1023;
        size_t off = (size_t)(w * NS + sh) * CHW + (size_t)hw * CDIM + c;
        s = fmaf((float)yH[off] + (float)yL[off],
                 cmn[(w * NS + sh) * HWDIM + hw], s);
    }
    part[((w * 5 + cc) * 8 + hs) * 128 + threadIdx.x] = s;
}

__global__ __launch_bounds__(128) void proto_red_k(const float* __restrict__ part,
                                                   float* __restrict__ out) {
    const int bid = blockIdx.x;
    float s = 0.f;
    #pragma unroll
    for (int hs = 0; hs < 8; ++hs) s += part[(bid * 8 + hs) * 128 + threadIdx.x];
    const int w = bid / 5, cc = bid % 5;
    out[w * CDIM + cc * 128 + threadIdx.x] = s * (1.0f / 5120.0f);
}

// ---------------------------------------------------------------------------
extern "C" void kernel_launch(void* const* d_in, const int* in_sizes, int n_in,
                              void* d_out, int out_size, void* d_ws, size_t ws_size,
                              hipStream_t stream) {
    const float* x5 = (const float*)d_in[0];
    const float* Wc = (const float*)d_in[1];
    const float* bc = (const float*)d_in[2];
    const float* Wq = (const float*)d_in[3];
    const float* bq = (const float*)d_in[4];
    const float* Wk = (const float*)d_in[5];
    const float* bk = (const float*)d_in[6];
    float* out = (float*)d_out;

    __bf16* big = (__bf16*)d_ws;
    __bf16* Ah = big;                                // X -> xq (hi)
    __bf16* Al = big + (size_t)NBIG;                 // X -> xq (lo)
    __bf16* Bh = big + (size_t)2 * NBIG;             // W2 head -> xk (hi)
    __bf16* Bl = big + (size_t)3 * NBIG;             // xk (lo)
    __bf16* W2H = Bh;
    __bf16* W2L = Bh + WSZ;
    __bf16* Ch = big + (size_t)4 * NBIG;             // WcT head -> y2 (hi)
    __bf16* Cl = big + (size_t)5 * NBIG;             // y2 (lo)
    __bf16* WcTH = Ch;
    __bf16* WcTL = Ch + WSZ;
    __bf16* wp = big + (size_t)6 * NBIG;
    __bf16* WqH = wp;
    __bf16* WqL = wp + WSZ;
    __bf16* WkH = wp + 2 * WSZ;
    __bf16* WkL = wp + 3 * WSZ;
    float* fp = (float*)(wp + 4 * WSZ);
    float* zbias = fp;                      // 640
    float* B2 = fp + 640;                   // 640
    float* bb2 = fp + 1280;                 // 1280
    float* gpart = fp + 2560;               // 128000
    float* invb = gpart + 128000;           // 25600
    float* seedsb = invb + 25600;           // 16000
    float* cmb = seedsb + 16000;            // 25600
    float* partb = cmb + 25600;             // 25600
    float* qn = partb + 25600;              // 25600
    float* knrow = qn + 25600;              // 25600
    float* kmaxb = knrow + 25600;           // 32
    int* gIdx = (int*)(kmaxb + 32);         // 25600
    int* gCnt = gIdx + BDIM * HWDIM;        // 32
    int* candCnt = gCnt + 32;               // 128000 int
    unsigned short* candIdx = (unsigned short*)(candCnt + NROWS);  // 128000*24 u16

    const int W4 = WSZ / 4;
    split_f32<<<dim3((W4 + 255) / 256), 256, 0, stream>>>(Wq, WqH, WqL, W4);
    split_f32<<<dim3((W4 + 255) / 256), 256, 0, stream>>>(Wk, WkH, WkL, W4);
    wtsplit<<<dim3(20, 20), 256, 0, stream>>>(Wc, WcTH, WcTL);   // (Wc+I)^T
    tsplit<<<dim3(32, 20, 25), 256, 0, stream>>>(x5, Ah, Al);    // X
    bias_prep<<<1, 640, 0, stream>>>(Wq, bc, bq, bk, zbias, B2, bb2);
    hipMemsetAsync(candCnt, 0, NROWS * sizeof(int), stream);

    // W2 = Wq * (Wc+I)
    gemm_sm<<<dim3(5, 5, 1), 256, 0, stream>>>(WqH, WqL, WcTH, WcTL, zbias,
                                               W2H, W2L);
    // pass1: y2 = W2 * x + B2
    conv_big<<<dim3(4, 5, 25), 256, 0, stream>>>(Ah, Al, W2H, W2L, W2H, W2L,
                                                 B2, Ch, Cl, Ch, Cl);
    // pass2: xq = Wq*y2 + bq (-> A), xk = Wk*y2 + bk (-> B)
    conv_big<<<dim3(4, 10, 25), 256, 0, stream>>>(Ch, Cl, WqH, WqL, WkH, WkL,
                                                  bb2, Ah, Al, Bh, Bl);

    qknorm_k<<<3200, 256, 0, stream>>>(Ah, Al, Bh, Bl, qn, knrow);
    kmax_k<<<25, 256, 0, stream>>>(knrow, kmaxb);
    attn_bf16<<<dim3(40, 5, 5), 256, 0, stream>>>(Ah, Bh, qn, kmaxb,
                                                  candCnt, candIdx);
    refine_k<<<NROWS / 4, 256, 0, stream>>>(Ah, Al, Bh, Bl, candCnt, candIdx,
                                            gpart);
    softmax_mask<<<25, 256, 0, stream>>>(gpart, gIdx, gCnt);
    nrm_k<<<1600, 256, 0, stream>>>(Ch, Cl, invb);
    seeds_k<<<25, 640, 0, stream>>>(Ch, Cl, invb, gIdx, gCnt, seedsb);
    cm_k<<<dim3(256, 5), 256, 0, stream>>>(Ch, Cl, invb, seedsb, cmb);
    minmax_kernel<<<25, 256, 0, stream>>>(cmb);
    proto_part_k<<<dim3(5, 5, 8), 128, 0, stream>>>(Ch, Cl, cmb, partb);
    proto_red_k<<<25, 128, 0, stream>>>(partb, out);
}